// Round 7
// baseline (262.171 us; speedup 1.0000x reference)
//
#include <hip/hip_runtime.h>
#include <hip/hip_bf16.h>

#define NEG_SLOPE 0.2f
#define BSHIFT 8                 // 256 nodes per bucket
#define MAXBUCK 256              // covers N up to 65536
#define ECAP 8192                // per-bucket slab capacity in staged[] (mean 4337, +55 sigma)
#define LDA 136                  // padded LDS row stride (bf16 elems): 272 B -> 16B-aligned rows, 2-way-free banks
#define SMEM_BYTES 52224         // union: gemm (128*LDA + 64*LDA)*2 = 52224 B > binA 35840 B

typedef __attribute__((ext_vector_type(8))) short bfrag;   // 8 bf16 (4 VGPRs)
typedef __attribute__((ext_vector_type(4))) float ffrag;   // 4 f32 acc

static __device__ __forceinline__ float b2f(unsigned short u){
  return __uint_as_float(((unsigned int)u) << 16);
}
static __device__ __forceinline__ unsigned short f2b16(float f){
  unsigned int u = __float_as_uint(f);
  return (unsigned short)((u + 0x7fffu + ((u >> 16) & 1u)) >> 16);   // RNE
}
static __device__ __forceinline__ unsigned int pack_bf2(float a, float b){
  return (unsigned int)f2b16(a) | ((unsigned int)f2b16(b) << 16);
}

// ---------------- setup: blocks 0-5 = weight prep, blocks 6+ = init (bcur zero, graph bounds) --
// prep: Wtc = bf16-T(lin_w @ w1) (blocks 0-3), bc = lin_b @ w1 (block 4), Wt2 = bf16-T(w2) (5).
// NOTE: 4-k float4-A blocking (round 12) spilled to scratch — do not reintroduce.
// NOTE: atomicAdd pooling in k_gat (round 15, and LDS-pre-reduced round 19) — both regressed;
//       round-19 fused pool + 16-deep GATED early issue took k_gat 44->71 us. Do not reintroduce.
// NOTE: direct global atomic-cursor scatter of esrc (round 17 k_scatter) wrote 64B/edge
//       (54 MB WRITE_SIZE, 56 us) — random 4B stores across XCD L2s; do not reintroduce.
__global__ __launch_bounds__(256) void k_setup(const float* __restrict__ lin_w,
    const float* __restrict__ lin_b, const float* __restrict__ w1,
    const float* __restrict__ w2, unsigned short* __restrict__ Wtc,
    float* __restrict__ bc, unsigned short* __restrict__ Wt2,
    const int* __restrict__ batch, int* __restrict__ bcur,
    int* __restrict__ gs, int* __restrict__ ge, int n){
  __shared__ float Wl[64 * 128];
  __shared__ float Al[32 * 128];
  const int t = threadIdx.x;
  if(blockIdx.x >= 6){
    int i = (blockIdx.x - 6) * 256 + t;
    if(i < MAXBUCK) bcur[i] = 0;
    if(i < n){
      int g = batch[i];
      if(i == 0){
        gs[g] = 0;
      } else {
        int gp = batch[i - 1];
        if(gp != g){ gs[g] = i; ge[gp] = i; }
      }
      if(i == n - 1) ge[g] = n;
    }
    return;
  }
  if(blockIdx.x == 4){
    if(t < 128){
      float s = 0.f;
      for(int k = 0; k < 128; k++) s += lin_b[k] * w1[k * 128 + t];
      bc[t] = s;
    }
    return;
  }
  if(blockIdx.x == 5){
    // transpose-convert w2 (f32 [k][n] row-major) -> Wt2 (bf16 [n][k])
    #pragma unroll
    for(int i = 0; i < 16; i++){
      int idx = t + i * 256;               // 0..4095 float4 units
      int k = idx >> 5, n0 = (idx & 31) * 4;
      float4 v = ((const float4*)w2)[idx];
      Wt2[(n0+0) * 128 + k] = f2b16(v.x);
      Wt2[(n0+1) * 128 + k] = f2b16(v.y);
      Wt2[(n0+2) * 128 + k] = f2b16(v.z);
      Wt2[(n0+3) * 128 + k] = f2b16(v.w);
    }
    return;
  }
  const int row0 = blockIdx.x * 32;
  #pragma unroll
  for(int i = 0; i < 8; i++){
    int idx = t + i * 256;
    int r = idx >> 6, kk = idx & 63;
    ((float2*)Al)[r * 64 + kk] = ((const float2*)lin_w)[(size_t)(row0 + r) * 64 + kk];
  }
  const int c0 = (t & 31) * 4;
  const int rb = (t >> 5) * 4;
  float acc[4][4] = {};
  const float4* W4 = (const float4*)w1;
  #pragma unroll
  for(int h = 0; h < 2; h++){
    if(h) __syncthreads();
    #pragma unroll
    for(int i = 0; i < 8; i++) ((float4*)Wl)[t + i * 256] = W4[h * 2048 + t + i * 256];
    __syncthreads();
    const int kb = h * 64;
    #pragma unroll 8
    for(int k = 0; k < 64; k++){
      float4 wv = *(const float4*)&Wl[k * 128 + c0];
      float a0 = Al[(rb+0)*128 + kb + k];
      float a1 = Al[(rb+1)*128 + kb + k];
      float a2 = Al[(rb+2)*128 + kb + k];
      float a3 = Al[(rb+3)*128 + kb + k];
      acc[0][0] += a0*wv.x; acc[0][1] += a0*wv.y; acc[0][2] += a0*wv.z; acc[0][3] += a0*wv.w;
      acc[1][0] += a1*wv.x; acc[1][1] += a1*wv.y; acc[1][2] += a1*wv.z; acc[1][3] += a1*wv.w;
      acc[2][0] += a2*wv.x; acc[2][1] += a2*wv.y; acc[2][2] += a2*wv.z; acc[2][3] += a2*wv.w;
      acc[3][0] += a3*wv.x; acc[3][1] += a3*wv.y; acc[3][2] += a3*wv.z; acc[3][3] += a3*wv.w;
    }
  }
  // write transposed bf16: Wtc[n][k]
  #pragma unroll
  for(int j = 0; j < 4; j++){
    int rg = row0 + rb + j;
    Wtc[(c0+0) * 128 + rg] = f2b16(acc[j][0]);
    Wtc[(c0+1) * 128 + rg] = f2b16(acc[j][1]);
    Wtc[(c0+2) * 128 + rg] = f2b16(acc[j][2]);
    Wtc[(c0+3) * 128 + rg] = f2b16(acc[j][3]);
  }
}

// ---------------- projection GEMM body (MFMA bf16): bf16-packed out + fused alpha (+opt bias) -
// W comes in pre-transposed bf16 [n][k] (from k_setup) -> staging is a pure vector copy.
// Shared memory passed in (dynamic union in the fused kernel, static in k_gemm2).
template<bool ABF>
static __device__ __forceinline__ void gemm_body(uint4* smem, const void* __restrict__ Av,
    const unsigned short* __restrict__ W, const float* __restrict__ a_src,
    const float* __restrict__ a_dst, const float* __restrict__ bias,
    unsigned int* __restrict__ hb,
    float* __restrict__ alpha_s, float* __restrict__ alpha_d, int nrows, int blk){
  unsigned short* Wt = (unsigned short*)smem;   // 128*LDA bf16
  unsigned short* Aw = Wt + 128 * LDA;          // 64*LDA bf16 (reused as out-stage)
  const int t = threadIdx.x;
  const int row0 = blk * 64;
  // stage W (already bf16 transposed): 32 KB vector copy with LDA padding
  {
    const uint4* Wv = (const uint4*)W;          // 128 rows x 16 uint4
    #pragma unroll
    for(int i = 0; i < 8; i++){
      int idx = t + i * 256;                    // 0..2047
      int nr = idx >> 4, c8 = idx & 15;
      *(uint4*)&Wt[nr * LDA + c8 * 8] = Wv[idx];
    }
  }
  // stage A to bf16
  if(ABF){
    #pragma unroll
    for(int i = 0; i < 8; i++){
      int idx = t + i * 256;                    // 0..2047, 32 uint2 per row
      int r = idx >> 5;
      int rg = row0 + r; if(rg >= nrows) rg = nrows - 1;
      uint2 v = ((const uint2*)Av)[(size_t)rg * 32 + (idx & 31)];
      unsigned int* dst = (unsigned int*)&Aw[r * LDA];
      dst[(idx & 31) * 2]     = v.x;
      dst[(idx & 31) * 2 + 1] = v.y;
    }
  } else {
    #pragma unroll
    for(int i = 0; i < 16; i++){
      int idx = t + i * 256;                    // 0..4095, 64 float2 per row
      int r = idx >> 6, c2 = idx & 63;
      int rg = row0 + r; if(rg >= nrows) rg = nrows - 1;
      float2 v = ((const float2*)Av)[(size_t)rg * 64 + c2];
      ((unsigned int*)&Aw[r * LDA])[c2] = pack_bf2(v.x, v.y);
    }
  }
  __syncthreads();

  const int lane = t & 63;
  const int wv = t >> 6;
  const int quad = lane >> 4, l = lane & 15;
  const int rw = wv * 16;
  bfrag a[4];
  #pragma unroll
  for(int kk = 0; kk < 4; kk++)
    a[kk] = *(const bfrag*)&Aw[(rw + l) * LDA + kk * 32 + quad * 8];
  ffrag acc[8];
  #pragma unroll
  for(int c = 0; c < 8; c++){
    ffrag z; z[0] = 0.f; z[1] = 0.f; z[2] = 0.f; z[3] = 0.f;
    acc[c] = z;
    #pragma unroll
    for(int kk = 0; kk < 4; kk++){
      bfrag b = *(const bfrag*)&Wt[(c * 16 + l) * LDA + kk * 32 + quad * 8];
      acc[c] = __builtin_amdgcn_mfma_f32_16x16x32_bf16(a[kk], b, acc[c], 0, 0, 0);
    }
  }
  // epilogue: bias (pre-alpha), alpha dots, pack
  float sdot[4] = {0.f,0.f,0.f,0.f}, ddot[4] = {0.f,0.f,0.f,0.f};
  #pragma unroll
  for(int c = 0; c < 8; c++){
    int col = c * 16 + l;
    float bv = bias ? bias[col] : 0.f;
    float as_ = a_src[col], ad_ = a_dst[col];
    #pragma unroll
    for(int r = 0; r < 4; r++){
      float v = acc[c][r] + bv;
      acc[c][r] = v;
      sdot[r] += v * as_;
      ddot[r] += v * ad_;
    }
  }
  #pragma unroll
  for(int r = 0; r < 4; r++){
    #pragma unroll
    for(int o = 1; o < 16; o <<= 1){
      sdot[r] += __shfl_xor(sdot[r], o);
      ddot[r] += __shfl_xor(ddot[r], o);
    }
  }
  if(l == 0){
    #pragma unroll
    for(int r = 0; r < 4; r++){
      int R = row0 + rw + quad * 4 + r;
      if(R < nrows){ alpha_s[R] = sdot[r]; alpha_d[R] = ddot[r]; }
    }
  }
  __syncthreads();                              // everyone done reading Aw/Wt
  unsigned short* ost = Aw;                     // 64 rows x 128 bf16 (unpadded)
  #pragma unroll
  for(int c = 0; c < 8; c++){
    int col = c * 16 + l;
    #pragma unroll
    for(int r = 0; r < 4; r++)
      ost[(rw + quad * 4 + r) * 128 + col] = f2b16(acc[c][r]);
  }
  __syncthreads();
  #pragma unroll
  for(int i = 0; i < 4; i++){
    int idx = t + i * 256;                      // 0..1023 uint4 units, 16 per row
    int r = idx >> 4;
    int rg = row0 + r;
    if(rg < nrows){
      uint4 v = ((const uint4*)ost)[idx];
      ((uint4*)&hb[(size_t)rg * 64])[idx & 15] = v;
    }
  }
}

// ---------------- binA body: LDS bucket sort into fixed slabs ---------------------------------
static __device__ __forceinline__ void binA_body(uint4* smem, const int* __restrict__ ei,
    int* __restrict__ bcur, uint2* __restrict__ staged, int E, int Etot, int blk){
  int* hist  = (int*)smem;
  int* scanb = hist + MAXBUCK;
  int* delta = scanb + MAXBUCK;
  uint2* buf = (uint2*)(delta + MAXBUCK);       // 4096 uint2 = 32 KB (offset 3072 B, 8B-aligned)
  const int t = threadIdx.x;
  const int base = blk * 4096;
  if(t < MAXBUCK) hist[t] = 0;
  __syncthreads();
  int myb[16], myi[16]; uint2 mye[16];
  #pragma unroll
  for(int k = 0; k < 16; k++){
    int e = base + t + k * 256;
    myb[k] = -1;
    if(e < Etot){
      int src, dst;
      if(e < E){ src = ei[e]; dst = ei[E + e]; }
      else { src = e - E; dst = src; }
      int b = dst >> BSHIFT;
      myi[k] = atomicAdd(&hist[b], 1);
      myb[k] = b;
      mye[k] = make_uint2((unsigned)src, (unsigned)dst);
    }
  }
  __syncthreads();
  if(t < MAXBUCK) scanb[t] = hist[t];
  __syncthreads();
  for(int off = 1; off < MAXBUCK; off <<= 1){
    int v = (t < MAXBUCK && t >= off) ? scanb[t - off] : 0;
    __syncthreads();
    if(t < MAXBUCK) scanb[t] += v;
    __syncthreads();
  }
  if(t < MAXBUCK){
    int excl = scanb[t] - hist[t];
    int gb = (hist[t] > 0) ? atomicAdd(&bcur[t], hist[t]) : 0;
    delta[t] = t * ECAP + gb - excl;            // fixed slab base + claimed offset
    scanb[t] = excl;
  }
  __syncthreads();
  #pragma unroll
  for(int k = 0; k < 16; k++){
    if(myb[k] >= 0) buf[scanb[myb[k]] + myi[k]] = mye[k];
  }
  __syncthreads();
  int total = min(4096, Etot - base);
  for(int i = t; i < total; i += 256){
    uint2 ed = buf[i];
    int b = (int)(ed.y >> BSHIFT);
    staged[i + delta[b]] = ed;                  // contiguous runs per bucket slab
  }
}

// ---------------- fused: gemm layer-1 (blocks < gbl) || binA (blocks >= gbl) ------------------
// Independent work, both depend only on k_setup -> overlap on the CU array (time ~= max not sum).
__global__ __launch_bounds__(256) void k_gemm1_binA(const void* __restrict__ Av,
    const unsigned short* __restrict__ W, const float* __restrict__ a_src,
    const float* __restrict__ a_dst, const float* __restrict__ bias,
    unsigned int* __restrict__ hb, float* __restrict__ alpha_s, float* __restrict__ alpha_d,
    int nrows, const int* __restrict__ ei, int* __restrict__ bcur,
    uint2* __restrict__ staged, int E, int Etot, int gbl){
  extern __shared__ uint4 smem_dyn[];
  if((int)blockIdx.x < gbl)
    gemm_body<false>(smem_dyn, Av, W, a_src, a_dst, bias, hb, alpha_s, alpha_d, nrows,
                     (int)blockIdx.x);
  else
    binA_body(smem_dyn, ei, bcur, staged, E, Etot, (int)blockIdx.x - gbl);
}

// ---------------- layer-2 GEMM (standalone) ----------------
__global__ __launch_bounds__(256) void k_gemm2(const void* __restrict__ Av,
    const unsigned short* __restrict__ W, const float* __restrict__ a_src,
    const float* __restrict__ a_dst, unsigned int* __restrict__ hb,
    float* __restrict__ alpha_s, float* __restrict__ alpha_d, int nrows){
  __shared__ uint4 smem_s[SMEM_BYTES / 16];
  gemm_body<true>(smem_s, Av, W, a_src, a_dst, nullptr, hb, alpha_s, alpha_d, nrows,
                  (int)blockIdx.x);
}

// per bucket: scan bucket counts (global offset), degree-count 256 nodes, scan, write rowptr,
// place edges into the dense esrc window.
__global__ __launch_bounds__(256) void k_binB(const uint2* __restrict__ staged,
    const int* __restrict__ bcur, int* __restrict__ rowptr, int* __restrict__ esrc, int n){
  __shared__ int sc[MAXBUCK];
  __shared__ int dcnt[1 << BSHIFT];
  __shared__ int doff[1 << BSHIFT];
  const int b = blockIdx.x;
  const int n0 = b << BSHIFT;
  const int t = threadIdx.x;
  // 256-wide scan of final bucket counts -> global CSR offset of this bucket
  int cv = bcur[t];
  sc[t] = cv;
  __syncthreads();
  for(int off = 1; off < MAXBUCK; off <<= 1){
    int x = (t >= off) ? sc[t - off] : 0;
    __syncthreads();
    sc[t] += x;
    __syncthreads();
  }
  const int cnt = bcur[b];
  const int lo = sc[b] - cnt;
  if(t == 0 && b == (int)gridDim.x - 1) rowptr[n] = sc[MAXBUCK - 1];
  const uint2* run = staged + (size_t)b * ECAP;
  dcnt[t] = 0;
  __syncthreads();
  for(int j = t; j < cnt; j += 256){
    uint2 ed = run[j];
    atomicAdd(&dcnt[(int)(ed.y) - n0], 1);
  }
  __syncthreads();
  int v = dcnt[t];
  doff[t] = v;
  __syncthreads();
  for(int off = 1; off < (1 << BSHIFT); off <<= 1){
    int x = (t >= off) ? doff[t - off] : 0;
    __syncthreads();
    doff[t] += x;
    __syncthreads();
  }
  int excl = doff[t] - v;
  int i = n0 + t;
  if(i < n) rowptr[i] = lo + excl;
  dcnt[t] = excl;                 // reuse as placement cursor
  __syncthreads();
  for(int j = t; j < cnt; j += 256){
    uint2 ed = run[j];
    int pos = atomicAdd(&dcnt[(int)(ed.y) - n0], 1);
    esrc[lo + pos] = (int)ed.x;
  }
}

// ---------------- full-wave GAT for one node (v2-proven path; used as rare fallback) ----------
static __device__ __forceinline__ void gat_fullwave(const unsigned int* __restrict__ hb,
    const int* __restrict__ esrc, const float* __restrict__ a_s,
    const float* __restrict__ a_d, const float* __restrict__ bias,
    unsigned int* __restrict__ hb_out, uint2* pairs_w,
    int w, int s0, int s1, int lane, int n){
  const int deg = s1 - s0;
  const float adv = a_d[w];
  float2 acc0 = make_float2(0.f, 0.f), acc1 = make_float2(0.f, 0.f);
  float2 acc2 = make_float2(0.f, 0.f), acc3 = make_float2(0.f, 0.f);
  if(deg <= 64){
    int srcl = 0;
    if(lane < deg){
      srcl = esrc[s0 + lane];
      srcl = ((unsigned)srcl < (unsigned)n) ? srcl : 0;
    }
    int i0 = __shfl(srcl, 0), i1 = __shfl(srcl, 1);
    int i2 = __shfl(srcl, 2), i3 = __shfl(srcl, 3);
    int i4 = __shfl(srcl, 4), i5 = __shfl(srcl, 5);
    int i6 = __shfl(srcl, 6), i7 = __shfl(srcl, 7);
    unsigned int u0 = hb[(((unsigned)i0) << 6) + lane];
    unsigned int u1 = hb[(((unsigned)i1) << 6) + lane];
    unsigned int u2 = hb[(((unsigned)i2) << 6) + lane];
    unsigned int u3 = hb[(((unsigned)i3) << 6) + lane];
    unsigned int u4 = hb[(((unsigned)i4) << 6) + lane];
    unsigned int u5 = hb[(((unsigned)i5) << 6) + lane];
    unsigned int u6 = hb[(((unsigned)i6) << 6) + lane];
    unsigned int u7 = hb[(((unsigned)i7) << 6) + lane];
    float e = -1e30f;
    if(lane < deg){
      float v = a_s[srcl] + adv;
      e = v > 0.f ? v : NEG_SLOPE * v;
    }
    float m = e;
    #pragma unroll
    for(int o = 32; o; o >>= 1) m = fmaxf(m, __shfl_xor(m, o));
    float wgt = (lane < deg) ? __expf(e - m) : 0.f;
    float den = wgt;
    #pragma unroll
    for(int o = 32; o; o >>= 1) den += __shfl_xor(den, o);
    float winv = (den > 0.f) ? wgt / den : 0.f;
    pairs_w[lane] = make_uint2((unsigned)srcl, __float_as_uint(winv));
    float w0 = __shfl(winv, 0), w1 = __shfl(winv, 1);
    float w2 = __shfl(winv, 2), w3 = __shfl(winv, 3);
    float w4 = __shfl(winv, 4), w5 = __shfl(winv, 5);
    float w6 = __shfl(winv, 6), w7 = __shfl(winv, 7);
    acc0.x += w0 * b2f((unsigned short)(u0 & 0xffffu)); acc0.y += w0 * b2f((unsigned short)(u0 >> 16));
    acc1.x += w1 * b2f((unsigned short)(u1 & 0xffffu)); acc1.y += w1 * b2f((unsigned short)(u1 >> 16));
    acc2.x += w2 * b2f((unsigned short)(u2 & 0xffffu)); acc2.y += w2 * b2f((unsigned short)(u2 >> 16));
    acc3.x += w3 * b2f((unsigned short)(u3 & 0xffffu)); acc3.y += w3 * b2f((unsigned short)(u3 >> 16));
    acc0.x += w4 * b2f((unsigned short)(u4 & 0xffffu)); acc0.y += w4 * b2f((unsigned short)(u4 >> 16));
    acc1.x += w5 * b2f((unsigned short)(u5 & 0xffffu)); acc1.y += w5 * b2f((unsigned short)(u5 >> 16));
    acc2.x += w6 * b2f((unsigned short)(u6 & 0xffffu)); acc2.y += w6 * b2f((unsigned short)(u6 >> 16));
    acc3.x += w7 * b2f((unsigned short)(u7 & 0xffffu)); acc3.y += w7 * b2f((unsigned short)(u7 >> 16));
    int jj = 8;
    for(; jj + 8 <= deg; jj += 8){
      uint2 p0 = pairs_w[jj + 0], p1 = pairs_w[jj + 1];
      uint2 p2 = pairs_w[jj + 2], p3 = pairs_w[jj + 3];
      uint2 p4 = pairs_w[jj + 4], p5 = pairs_w[jj + 5];
      uint2 p6 = pairs_w[jj + 6], p7 = pairs_w[jj + 7];
      unsigned int v0 = hb[(p0.x << 6) + lane];
      unsigned int v1 = hb[(p1.x << 6) + lane];
      unsigned int v2 = hb[(p2.x << 6) + lane];
      unsigned int v3 = hb[(p3.x << 6) + lane];
      unsigned int v4 = hb[(p4.x << 6) + lane];
      unsigned int v5 = hb[(p5.x << 6) + lane];
      unsigned int v6 = hb[(p6.x << 6) + lane];
      unsigned int v7 = hb[(p7.x << 6) + lane];
      float q0 = __uint_as_float(p0.y), q1 = __uint_as_float(p1.y);
      float q2 = __uint_as_float(p2.y), q3 = __uint_as_float(p3.y);
      float q4 = __uint_as_float(p4.y), q5 = __uint_as_float(p5.y);
      float q6 = __uint_as_float(p6.y), q7 = __uint_as_float(p7.y);
      acc0.x += q0 * b2f((unsigned short)(v0 & 0xffffu)); acc0.y += q0 * b2f((unsigned short)(v0 >> 16));
      acc1.x += q1 * b2f((unsigned short)(v1 & 0xffffu)); acc1.y += q1 * b2f((unsigned short)(v1 >> 16));
      acc2.x += q2 * b2f((unsigned short)(v2 & 0xffffu)); acc2.y += q2 * b2f((unsigned short)(v2 >> 16));
      acc3.x += q3 * b2f((unsigned short)(v3 & 0xffffu)); acc3.y += q3 * b2f((unsigned short)(v3 >> 16));
      acc0.x += q4 * b2f((unsigned short)(v4 & 0xffffu)); acc0.y += q4 * b2f((unsigned short)(v4 >> 16));
      acc1.x += q5 * b2f((unsigned short)(v5 & 0xffffu)); acc1.y += q5 * b2f((unsigned short)(v5 >> 16));
      acc2.x += q6 * b2f((unsigned short)(v6 & 0xffffu)); acc2.y += q6 * b2f((unsigned short)(v6 >> 16));
      acc3.x += q7 * b2f((unsigned short)(v7 & 0xffffu)); acc3.y += q7 * b2f((unsigned short)(v7 >> 16));
    }
    for(; jj < deg; jj++){
      uint2 p = pairs_w[jj];
      unsigned int v = hb[(p.x << 6) + lane];
      float q = __uint_as_float(p.y);
      acc0.x += q * b2f((unsigned short)(v & 0xffffu));
      acc0.y += q * b2f((unsigned short)(v >> 16));
    }
  } else {
    float m = -1e30f;
    for(int j = s0 + lane; j < s1; j += 64){
      int s = esrc[j]; s = ((unsigned)s < (unsigned)n) ? s : 0;
      float e = a_s[s] + adv;
      e = e > 0.f ? e : NEG_SLOPE * e;
      m = fmaxf(m, e);
    }
    #pragma unroll
    for(int o = 32; o; o >>= 1) m = fmaxf(m, __shfl_xor(m, o));
    float den = 0.f;
    for(int j = s0 + lane; j < s1; j += 64){
      int s = esrc[j]; s = ((unsigned)s < (unsigned)n) ? s : 0;
      float e = a_s[s] + adv;
      e = e > 0.f ? e : NEG_SLOPE * e;
      den += __expf(e - m);
    }
    #pragma unroll
    for(int o = 32; o; o >>= 1) den += __shfl_xor(den, o);
    float inv = (den > 0.f) ? 1.f / den : 0.f;
    for(int j = s0; j < s1; j++){
      int s = esrc[j]; s = ((unsigned)s < (unsigned)n) ? s : 0;
      float e = a_s[s] + adv;
      e = e > 0.f ? e : NEG_SLOPE * e;
      float wv = __expf(e - m) * inv;
      unsigned int u = hb[(((unsigned)s) << 6) + lane];
      acc0.x += wv * b2f((unsigned short)(u & 0xffffu));
      acc0.y += wv * b2f((unsigned short)(u >> 16));
    }
  }
  float2 bl = ((const float2*)bias)[lane];
  float ox = (acc0.x + acc1.x) + (acc2.x + acc3.x) + bl.x;
  float oy = (acc0.y + acc1.y) + (acc2.y + acc3.y) + bl.y;
  ox = 0.5f * (ox + fabsf(ox));   // NaN-transparent relu
  oy = 0.5f * (oy + fabsf(oy));
  hb_out[(size_t)w * 64 + lane] = pack_bf2(ox, oy);
}

// 8 features accumulate for one dual-row uint4 fragment
#define ACC8(U, WQ) do{ float _w = (WQ); \
  acc0.x += _w * b2f((unsigned short)((U).x & 0xffffu)); \
  acc0.y += _w * b2f((unsigned short)((U).x >> 16)); \
  acc0.z += _w * b2f((unsigned short)((U).y & 0xffffu)); \
  acc0.w += _w * b2f((unsigned short)((U).y >> 16)); \
  acc1.x += _w * b2f((unsigned short)((U).z & 0xffffu)); \
  acc1.y += _w * b2f((unsigned short)((U).z >> 16)); \
  acc1.z += _w * b2f((unsigned short)((U).w & 0xffffu)); \
  acc1.w += _w * b2f((unsigned short)((U).w >> 16)); }while(0)

// ---------------- GAT: 2 nodes/wave, ALL 32 edges in ONE gather round ------------------------
// Lanes 0-31 node A, 32-63 node B. Within a half: lanes 0-15 handle even edges, 16-31 odd
// (sub = hl>>4), each reading 16 B (8 features) of the row -> one load instr covers 2 edges,
// and 16 dual-loads cover edges 0..31 = ALL edges of a deg<=32 node. No LDS stash, no second
// dependent round, no tail loops. Padding lanes (hl>=deg) have srcl=0 -> all their loads hit
// row 0's four lines (permanently cache-hot); their weights are exactly 0 via winv shuffle.
// Pair-split recombined with 8 shfl_xor(16). deg>32 -> wave-uniform full-wave fallback (~1e-4).
__global__ __launch_bounds__(256) void k_gat(const unsigned int* __restrict__ hb,
    const int* __restrict__ rowptr, const int* __restrict__ esrc,
    const float* __restrict__ a_s, const float* __restrict__ a_d,
    const float* __restrict__ bias, unsigned int* __restrict__ hb_out, int n, int Etot){
  __shared__ uint2 pairs[4][64];              // used only by the rare fallback path
  const int t = threadIdx.x;
  const int lane = t & 63;
  const int wvid = t >> 6;
  const int nA = blockIdx.x * 8 + wvid * 2;   // 8 nodes per block (2 per wave)
  if(nA >= n) return;
  const int nB = nA + 1;
  int r0 = rowptr[nA];
  int r1 = rowptr[nA + 1];
  int r2 = (nB < n) ? rowptr[nB + 1] : r1;
  r0 = max(0, min(r0, Etot));
  r1 = max(r0, min(r1, Etot));
  r2 = max(r1, min(r2, Etot));
  const int degA = r1 - r0, degB = r2 - r1;

  if(degA <= 32 && degB <= 32){
    const int half = lane >> 5;               // 0: node A, 1: node B
    const int hl = lane & 31;
    const int sub = hl >> 4;                  // 0: even edge of pair, 1: odd edge
    const int fl = hl & 15;                   // 16B feature chunk (features 8fl..8fl+7)
    const int w = nA + half;
    const int s0 = half ? r1 : r0;
    const int deg = half ? degB : degA;
    const float adv = (w < n) ? a_d[w] : 0.f;
    const uint4* __restrict__ hb4 = (const uint4*)hb;   // row = 16 uint4
    float4 acc0 = make_float4(0.f, 0.f, 0.f, 0.f);
    float4 acc1 = make_float4(0.f, 0.f, 0.f, 0.f);

    int srcl = 0;
    if(hl < deg){
      srcl = esrc[s0 + hl];
      srcl = ((unsigned)srcl < (unsigned)n) ? srcl : 0;
    }
    const int hb0 = lane & 32;
    // ALL edges 0..31 via 16 dual-row loads, issued before softmax
    int e0  = __shfl(srcl, hb0 + 0  + sub);
    int e1  = __shfl(srcl, hb0 + 2  + sub);
    int e2  = __shfl(srcl, hb0 + 4  + sub);
    int e3  = __shfl(srcl, hb0 + 6  + sub);
    int e4  = __shfl(srcl, hb0 + 8  + sub);
    int e5  = __shfl(srcl, hb0 + 10 + sub);
    int e6  = __shfl(srcl, hb0 + 12 + sub);
    int e7  = __shfl(srcl, hb0 + 14 + sub);
    int e8  = __shfl(srcl, hb0 + 16 + sub);
    int e9  = __shfl(srcl, hb0 + 18 + sub);
    int e10 = __shfl(srcl, hb0 + 20 + sub);
    int e11 = __shfl(srcl, hb0 + 22 + sub);
    int e12 = __shfl(srcl, hb0 + 24 + sub);
    int e13 = __shfl(srcl, hb0 + 26 + sub);
    int e14 = __shfl(srcl, hb0 + 28 + sub);
    int e15 = __shfl(srcl, hb0 + 30 + sub);
    uint4 u0  = hb4[(((unsigned)e0)  << 4) + fl];
    uint4 u1  = hb4[(((unsigned)e1)  << 4) + fl];
    uint4 u2  = hb4[(((unsigned)e2)  << 4) + fl];
    uint4 u3  = hb4[(((unsigned)e3)  << 4) + fl];
    uint4 u4  = hb4[(((unsigned)e4)  << 4) + fl];
    uint4 u5  = hb4[(((unsigned)e5)  << 4) + fl];
    uint4 u6  = hb4[(((unsigned)e6)  << 4) + fl];
    uint4 u7  = hb4[(((unsigned)e7)  << 4) + fl];
    uint4 u8  = hb4[(((unsigned)e8)  << 4) + fl];
    uint4 u9  = hb4[(((unsigned)e9)  << 4) + fl];
    uint4 u10 = hb4[(((unsigned)e10) << 4) + fl];
    uint4 u11 = hb4[(((unsigned)e11) << 4) + fl];
    uint4 u12 = hb4[(((unsigned)e12) << 4) + fl];
    uint4 u13 = hb4[(((unsigned)e13) << 4) + fl];
    uint4 u14 = hb4[(((unsigned)e14) << 4) + fl];
    uint4 u15 = hb4[(((unsigned)e15) << 4) + fl];
    // softmax (hidden under load latency); reductions stay within the 32-lane half
    float e = -1e30f;
    if(hl < deg){
      float v = a_s[srcl] + adv;
      e = v > 0.f ? v : NEG_SLOPE * v;
    }
    float m = e;
    #pragma unroll
    for(int o = 16; o; o >>= 1) m = fmaxf(m, __shfl_xor(m, o));
    float wgt = (hl < deg) ? __expf(e - m) : 0.f;
    float den = wgt;
    #pragma unroll
    for(int o = 16; o; o >>= 1) den += __shfl_xor(den, o);
    float winv = (den > 0.f) ? wgt / den : 0.f;   // lanes >= deg -> 0
    // consume all 16 dual fragments (weights 0 beyond deg)
    ACC8(u0,  __shfl(winv, hb0 + 0  + sub));
    ACC8(u1,  __shfl(winv, hb0 + 2  + sub));
    ACC8(u2,  __shfl(winv, hb0 + 4  + sub));
    ACC8(u3,  __shfl(winv, hb0 + 6  + sub));
    ACC8(u4,  __shfl(winv, hb0 + 8  + sub));
    ACC8(u5,  __shfl(winv, hb0 + 10 + sub));
    ACC8(u6,  __shfl(winv, hb0 + 12 + sub));
    ACC8(u7,  __shfl(winv, hb0 + 14 + sub));
    ACC8(u8,  __shfl(winv, hb0 + 16 + sub));
    ACC8(u9,  __shfl(winv, hb0 + 18 + sub));
    ACC8(u10, __shfl(winv, hb0 + 20 + sub));
    ACC8(u11, __shfl(winv, hb0 + 22 + sub));
    ACC8(u12, __shfl(winv, hb0 + 24 + sub));
    ACC8(u13, __shfl(winv, hb0 + 26 + sub));
    ACC8(u14, __shfl(winv, hb0 + 28 + sub));
    ACC8(u15, __shfl(winv, hb0 + 30 + sub));
    // recombine even/odd edge sub-accumulators
    acc0.x += __shfl_xor(acc0.x, 16); acc0.y += __shfl_xor(acc0.y, 16);
    acc0.z += __shfl_xor(acc0.z, 16); acc0.w += __shfl_xor(acc0.w, 16);
    acc1.x += __shfl_xor(acc1.x, 16); acc1.y += __shfl_xor(acc1.y, 16);
    acc1.z += __shfl_xor(acc1.z, 16); acc1.w += __shfl_xor(acc1.w, 16);
    if(w < n && sub == 0){
      float4 b0 = ((const float4*)bias)[2 * fl];
      float4 b1 = ((const float4*)bias)[2 * fl + 1];
      float f0 = acc0.x + b0.x, f1 = acc0.y + b0.y;
      float f2 = acc0.z + b0.z, f3 = acc0.w + b0.w;
      float f4 = acc1.x + b1.x, f5 = acc1.y + b1.y;
      float f6 = acc1.z + b1.z, f7 = acc1.w + b1.w;
      f0 = 0.5f * (f0 + fabsf(f0)); f1 = 0.5f * (f1 + fabsf(f1));   // NaN-transparent relu
      f2 = 0.5f * (f2 + fabsf(f2)); f3 = 0.5f * (f3 + fabsf(f3));
      f4 = 0.5f * (f4 + fabsf(f4)); f5 = 0.5f * (f5 + fabsf(f5));
      f6 = 0.5f * (f6 + fabsf(f6)); f7 = 0.5f * (f7 + fabsf(f7));
      ((uint4*)hb_out)[((size_t)w << 4) + fl] =
        make_uint4(pack_bf2(f0, f1), pack_bf2(f2, f3), pack_bf2(f4, f5), pack_bf2(f6, f7));
    }
  } else {
    // rare: some half has deg > 32 -> full-wave per node
    gat_fullwave(hb, esrc, a_s, a_d, bias, hb_out, &pairs[wvid][0], nA, r0, r1, lane, n);
    if(nB < n)
      gat_fullwave(hb, esrc, a_s, a_d, bias, hb_out, &pairs[wvid][0], nB, r1, r2, lane, n);
  }
}

// ---------------- mean-pool (bf16 h) + fused head ----------------
__global__ __launch_bounds__(512) void k_poolout(const unsigned int* __restrict__ h2,
    const int* __restrict__ gs, const int* __restrict__ ge,
    const float* __restrict__ out_w, const float* __restrict__ out_b,
    float* __restrict__ out, int n){
  const int g = blockIdx.x;
  const int t = threadIdx.x;
  const int f2 = t & 63;          // packed-uint column (features 2*f2, 2*f2+1)
  const int rr = t >> 6;          // row phase 0..7
  int s = gs[g], e = ge[g];
  s = max(0, min(s, n)); e = max(s, min(e, n));
  float sx = 0.f, sy = 0.f;
  for(int i = s + rr; i < e; i += 8){
    unsigned int u = h2[(size_t)i * 64 + f2];
    sx += b2f((unsigned short)(u & 0xffffu));
    sy += b2f((unsigned short)(u >> 16));
  }
  __shared__ float part[8 * 128];
  part[rr * 128 + 2 * f2]     = sx;
  part[rr * 128 + 2 * f2 + 1] = sy;
  __syncthreads();
  __shared__ float red[2];
  if(t < 128){
    float tot = 0.f;
    #pragma unroll
    for(int r = 0; r < 8; r++) tot += part[r * 128 + t];
    int c = e - s;
    float invc = (c > 0) ? 1.f / (float)c : 0.f;
    float v = tot * invc * out_w[t];
    #pragma unroll
    for(int o = 32; o; o >>= 1) v += __shfl_xor(v, o);
    if((t & 63) == 0) red[t >> 6] = v;
  }
  __syncthreads();
  if(t == 0) out[g] = red[0] + red[1] + out_b[0];
}

extern "C" void kernel_launch(void* const* d_in, const int* in_sizes, int n_in,
                              void* d_out, int out_size, void* d_ws, size_t ws_size,
                              hipStream_t stream){
  const float* x     = (const float*)d_in[0];
  const int*   ei    = (const int*)d_in[1];
  const int*   batch = (const int*)d_in[2];
  const float* lin_w = (const float*)d_in[3];
  const float* lin_b = (const float*)d_in[4];
  const float* w1    = (const float*)d_in[5];
  const float* as1   = (const float*)d_in[6];
  const float* ad1   = (const float*)d_in[7];
  const float* b1    = (const float*)d_in[8];
  const float* w2    = (const float*)d_in[9];
  const float* as2   = (const float*)d_in[10];
  const float* ad2   = (const float*)d_in[11];
  const float* b2    = (const float*)d_in[12];
  const float* ow    = (const float*)d_in[13];
  const float* ob    = (const float*)d_in[14];
  float* out = (float*)d_out;

  const int N = in_sizes[0] / 128;
  const int E = in_sizes[1] / 2;
  const int Etot = E + N;
  const int G = out_size;
  const int nbuck = (N + (1 << BSHIFT) - 1) >> BSHIFT;

  auto a16 = [](size_t v){ return (v + 15) & ~(size_t)15; };
  char* p = (char*)d_ws;
  int*   rowptr  = (int*)p;   p += a16((size_t)(N + 1) * 4);
  int*   bcur    = (int*)p;   p += a16((size_t)MAXBUCK * 4);
  int*   gs      = (int*)p;   p += a16((size_t)G * 4);
  int*   ge      = (int*)p;   p += a16((size_t)G * 4);
  float* alpha_s = (float*)p; p += a16((size_t)N * 4);
  float* alpha_d = (float*)p; p += a16((size_t)N * 4);
  unsigned short* Wtc = (unsigned short*)p; p += (size_t)128 * 128 * 2;  // bf16-T(Win@W1)
  float* bc      = (float*)p; p += (size_t)128 * 4;                      // b_in@W1
  unsigned short* Wt2 = (unsigned short*)p; p += (size_t)128 * 128 * 2;  // bf16-T(w2)
  int*   esrc    = (int*)p;   p += a16((size_t)Etot * 4);
  uint2* staged  = (uint2*)p; p += (size_t)MAXBUCK * ECAP * 8;           // fixed slabs
  unsigned int* hb  = (unsigned int*)p; p += (size_t)N * 64 * 4;  // projection, bf16-packed
  unsigned int* hb2 = (unsigned int*)p; p += (size_t)N * 64 * 4;  // h1 / h2, bf16-packed

  const int cbl = (Etot + 4095) / 4096;
  const int gbl = (N + 63) / 64;
  const int wbl = (N + 7) / 8;

  k_setup<<<6 + (N + 255) / 256, 256, 0, stream>>>(lin_w, lin_b, w1, w2, Wtc, bc, Wt2,
                                                   batch, bcur, gs, ge, N);
  // gemm layer-1 and binA are independent (both depend only on setup) -> one overlapped launch
  k_gemm1_binA<<<gbl + cbl, 256, SMEM_BYTES, stream>>>(x, Wtc, as1, ad1, bc, hb,
                                                       alpha_s, alpha_d, N,
                                                       ei, bcur, staged, E, Etot, gbl);
  k_binB<<<nbuck, 256, 0, stream>>>(staged, bcur, rowptr, esrc, N);
  k_gat<<<wbl, 256, 0, stream>>>(hb, rowptr, esrc, alpha_s, alpha_d, b1, hb2, N, Etot);
  k_gemm2<<<gbl, 256, 0, stream>>>(hb2, Wt2, as2, ad2, hb, alpha_s, alpha_d, N);
  k_gat<<<wbl, 256, 0, stream>>>(hb, rowptr, esrc, alpha_s, alpha_d, b2, hb2, N, Etot);
  k_poolout<<<G, 512, 0, stream>>>(hb2, gs, ge, ow, ob, out, N);
}

// Round 8
// 257.391 us; speedup vs baseline: 1.0186x; 1.0186x over previous
//
#include <hip/hip_runtime.h>
#include <hip/hip_bf16.h>

#define NEG_SLOPE 0.2f
#define BSHIFT 8                 // 256 nodes per bucket
#define MAXBUCK 256              // covers N up to 65536
#define ECAP 8192                // per-bucket slab capacity in staged[] (mean 4337, +55 sigma)
#define LDA 136                  // padded LDS row stride (bf16 elems): 272 B -> 16B-aligned rows, 2-way-free banks
#define SMEM_BYTES 52224         // union: gemm (128*LDA + 64*LDA)*2 = 52224 B > binA 35840 B

typedef __attribute__((ext_vector_type(8))) short bfrag;   // 8 bf16 (4 VGPRs)
typedef __attribute__((ext_vector_type(4))) float ffrag;   // 4 f32 acc

static __device__ __forceinline__ float b2f(unsigned short u){
  return __uint_as_float(((unsigned int)u) << 16);
}
static __device__ __forceinline__ unsigned short f2b16(float f){
  unsigned int u = __float_as_uint(f);
  return (unsigned short)((u + 0x7fffu + ((u >> 16) & 1u)) >> 16);   // RNE
}
static __device__ __forceinline__ unsigned int pack_bf2(float a, float b){
  return (unsigned int)f2b16(a) | ((unsigned int)f2b16(b) << 16);
}

// ---------------- setup: blocks 0-5 = weight prep, blocks 6+ = init (bcur zero, graph bounds) --
// prep: Wtc = bf16-T(lin_w @ w1) (blocks 0-3), bc = lin_b @ w1 (block 4), Wt2 = bf16-T(w2) (5).
// NOTE: 4-k float4-A blocking (round 12) spilled to scratch — do not reintroduce.
// NOTE: atomicAdd pooling in k_gat (rounds 15/19) regressed — do not reintroduce.
// NOTE: direct global atomic-cursor scatter of esrc (round 17) wrote 64B/edge — do not reintroduce.
// NOTE: 16-outstanding-uint4 k_gat (round 21) dropped occupancy 64->31%, 43->48.5 us — reverted.
__global__ __launch_bounds__(256) void k_setup(const float* __restrict__ lin_w,
    const float* __restrict__ lin_b, const float* __restrict__ w1,
    const float* __restrict__ w2, unsigned short* __restrict__ Wtc,
    float* __restrict__ bc, unsigned short* __restrict__ Wt2,
    const int* __restrict__ batch, int* __restrict__ bcur,
    int* __restrict__ gs, int* __restrict__ ge, int n){
  __shared__ float Wl[64 * 128];
  __shared__ float Al[32 * 128];
  const int t = threadIdx.x;
  if(blockIdx.x >= 6){
    int i = (blockIdx.x - 6) * 256 + t;
    if(i < MAXBUCK) bcur[i] = 0;
    if(i < n){
      int g = batch[i];
      if(i == 0){
        gs[g] = 0;
      } else {
        int gp = batch[i - 1];
        if(gp != g){ gs[g] = i; ge[gp] = i; }
      }
      if(i == n - 1) ge[g] = n;
    }
    return;
  }
  if(blockIdx.x == 4){
    if(t < 128){
      float s = 0.f;
      for(int k = 0; k < 128; k++) s += lin_b[k] * w1[k * 128 + t];
      bc[t] = s;
    }
    return;
  }
  if(blockIdx.x == 5){
    // transpose-convert w2 (f32 [k][n] row-major) -> Wt2 (bf16 [n][k])
    #pragma unroll
    for(int i = 0; i < 16; i++){
      int idx = t + i * 256;               // 0..4095 float4 units
      int k = idx >> 5, n0 = (idx & 31) * 4;
      float4 v = ((const float4*)w2)[idx];
      Wt2[(n0+0) * 128 + k] = f2b16(v.x);
      Wt2[(n0+1) * 128 + k] = f2b16(v.y);
      Wt2[(n0+2) * 128 + k] = f2b16(v.z);
      Wt2[(n0+3) * 128 + k] = f2b16(v.w);
    }
    return;
  }
  const int row0 = blockIdx.x * 32;
  #pragma unroll
  for(int i = 0; i < 8; i++){
    int idx = t + i * 256;
    int r = idx >> 6, kk = idx & 63;
    ((float2*)Al)[r * 64 + kk] = ((const float2*)lin_w)[(size_t)(row0 + r) * 64 + kk];
  }
  const int c0 = (t & 31) * 4;
  const int rb = (t >> 5) * 4;
  float acc[4][4] = {};
  const float4* W4 = (const float4*)w1;
  #pragma unroll
  for(int h = 0; h < 2; h++){
    if(h) __syncthreads();
    #pragma unroll
    for(int i = 0; i < 8; i++) ((float4*)Wl)[t + i * 256] = W4[h * 2048 + t + i * 256];
    __syncthreads();
    const int kb = h * 64;
    #pragma unroll 8
    for(int k = 0; k < 64; k++){
      float4 wv = *(const float4*)&Wl[k * 128 + c0];
      float a0 = Al[(rb+0)*128 + kb + k];
      float a1 = Al[(rb+1)*128 + kb + k];
      float a2 = Al[(rb+2)*128 + kb + k];
      float a3 = Al[(rb+3)*128 + kb + k];
      acc[0][0] += a0*wv.x; acc[0][1] += a0*wv.y; acc[0][2] += a0*wv.z; acc[0][3] += a0*wv.w;
      acc[1][0] += a1*wv.x; acc[1][1] += a1*wv.y; acc[1][2] += a1*wv.z; acc[1][3] += a1*wv.w;
      acc[2][0] += a2*wv.x; acc[2][1] += a2*wv.y; acc[2][2] += a2*wv.z; acc[2][3] += a2*wv.w;
      acc[3][0] += a3*wv.x; acc[3][1] += a3*wv.y; acc[3][2] += a3*wv.z; acc[3][3] += a3*wv.w;
    }
  }
  // write transposed bf16: Wtc[n][k]
  #pragma unroll
  for(int j = 0; j < 4; j++){
    int rg = row0 + rb + j;
    Wtc[(c0+0) * 128 + rg] = f2b16(acc[j][0]);
    Wtc[(c0+1) * 128 + rg] = f2b16(acc[j][1]);
    Wtc[(c0+2) * 128 + rg] = f2b16(acc[j][2]);
    Wtc[(c0+3) * 128 + rg] = f2b16(acc[j][3]);
  }
}

// ---------------- projection GEMM body (MFMA bf16): bf16-packed out + fused alpha (+opt bias) -
template<bool ABF>
static __device__ __forceinline__ void gemm_body(uint4* smem, const void* __restrict__ Av,
    const unsigned short* __restrict__ W, const float* __restrict__ a_src,
    const float* __restrict__ a_dst, const float* __restrict__ bias,
    unsigned int* __restrict__ hb,
    float* __restrict__ alpha_s, float* __restrict__ alpha_d, int nrows, int blk){
  unsigned short* Wt = (unsigned short*)smem;   // 128*LDA bf16
  unsigned short* Aw = Wt + 128 * LDA;          // 64*LDA bf16 (reused as out-stage)
  const int t = threadIdx.x;
  const int row0 = blk * 64;
  // stage W (already bf16 transposed): 32 KB vector copy with LDA padding
  {
    const uint4* Wv = (const uint4*)W;          // 128 rows x 16 uint4
    #pragma unroll
    for(int i = 0; i < 8; i++){
      int idx = t + i * 256;                    // 0..2047
      int nr = idx >> 4, c8 = idx & 15;
      *(uint4*)&Wt[nr * LDA + c8 * 8] = Wv[idx];
    }
  }
  // stage A to bf16
  if(ABF){
    #pragma unroll
    for(int i = 0; i < 8; i++){
      int idx = t + i * 256;                    // 0..2047, 32 uint2 per row
      int r = idx >> 5;
      int rg = row0 + r; if(rg >= nrows) rg = nrows - 1;
      uint2 v = ((const uint2*)Av)[(size_t)rg * 32 + (idx & 31)];
      unsigned int* dst = (unsigned int*)&Aw[r * LDA];
      dst[(idx & 31) * 2]     = v.x;
      dst[(idx & 31) * 2 + 1] = v.y;
    }
  } else {
    #pragma unroll
    for(int i = 0; i < 16; i++){
      int idx = t + i * 256;                    // 0..4095, 64 float2 per row
      int r = idx >> 6, c2 = idx & 63;
      int rg = row0 + r; if(rg >= nrows) rg = nrows - 1;
      float2 v = ((const float2*)Av)[(size_t)rg * 64 + c2];
      ((unsigned int*)&Aw[r * LDA])[c2] = pack_bf2(v.x, v.y);
    }
  }
  __syncthreads();

  const int lane = t & 63;
  const int wv = t >> 6;
  const int quad = lane >> 4, l = lane & 15;
  const int rw = wv * 16;
  bfrag a[4];
  #pragma unroll
  for(int kk = 0; kk < 4; kk++)
    a[kk] = *(const bfrag*)&Aw[(rw + l) * LDA + kk * 32 + quad * 8];
  ffrag acc[8];
  #pragma unroll
  for(int c = 0; c < 8; c++){
    ffrag z; z[0] = 0.f; z[1] = 0.f; z[2] = 0.f; z[3] = 0.f;
    acc[c] = z;
    #pragma unroll
    for(int kk = 0; kk < 4; kk++){
      bfrag b = *(const bfrag*)&Wt[(c * 16 + l) * LDA + kk * 32 + quad * 8];
      acc[c] = __builtin_amdgcn_mfma_f32_16x16x32_bf16(a[kk], b, acc[c], 0, 0, 0);
    }
  }
  // epilogue: bias (pre-alpha), alpha dots, pack
  float sdot[4] = {0.f,0.f,0.f,0.f}, ddot[4] = {0.f,0.f,0.f,0.f};
  #pragma unroll
  for(int c = 0; c < 8; c++){
    int col = c * 16 + l;
    float bv = bias ? bias[col] : 0.f;
    float as_ = a_src[col], ad_ = a_dst[col];
    #pragma unroll
    for(int r = 0; r < 4; r++){
      float v = acc[c][r] + bv;
      acc[c][r] = v;
      sdot[r] += v * as_;
      ddot[r] += v * ad_;
    }
  }
  #pragma unroll
  for(int r = 0; r < 4; r++){
    #pragma unroll
    for(int o = 1; o < 16; o <<= 1){
      sdot[r] += __shfl_xor(sdot[r], o);
      ddot[r] += __shfl_xor(ddot[r], o);
    }
  }
  if(l == 0){
    #pragma unroll
    for(int r = 0; r < 4; r++){
      int R = row0 + rw + quad * 4 + r;
      if(R < nrows){ alpha_s[R] = sdot[r]; alpha_d[R] = ddot[r]; }
    }
  }
  __syncthreads();                              // everyone done reading Aw/Wt
  unsigned short* ost = Aw;                     // 64 rows x 128 bf16 (unpadded)
  #pragma unroll
  for(int c = 0; c < 8; c++){
    int col = c * 16 + l;
    #pragma unroll
    for(int r = 0; r < 4; r++)
      ost[(rw + quad * 4 + r) * 128 + col] = f2b16(acc[c][r]);
  }
  __syncthreads();
  #pragma unroll
  for(int i = 0; i < 4; i++){
    int idx = t + i * 256;                      // 0..1023 uint4 units, 16 per row
    int r = idx >> 4;
    int rg = row0 + r;
    if(rg < nrows){
      uint4 v = ((const uint4*)ost)[idx];
      ((uint4*)&hb[(size_t)rg * 64])[idx & 15] = v;
    }
  }
}

// ---------------- binA body: LDS bucket sort into fixed slabs ---------------------------------
static __device__ __forceinline__ void binA_body(uint4* smem, const int* __restrict__ ei,
    int* __restrict__ bcur, uint2* __restrict__ staged, int E, int Etot, int blk){
  int* hist  = (int*)smem;
  int* scanb = hist + MAXBUCK;
  int* delta = scanb + MAXBUCK;
  uint2* buf = (uint2*)(delta + MAXBUCK);       // 4096 uint2 = 32 KB (offset 3072 B, 8B-aligned)
  const int t = threadIdx.x;
  const int base = blk * 4096;
  if(t < MAXBUCK) hist[t] = 0;
  __syncthreads();
  int myb[16], myi[16]; uint2 mye[16];
  #pragma unroll
  for(int k = 0; k < 16; k++){
    int e = base + t + k * 256;
    myb[k] = -1;
    if(e < Etot){
      int src, dst;
      if(e < E){ src = ei[e]; dst = ei[E + e]; }
      else { src = e - E; dst = src; }
      int b = dst >> BSHIFT;
      myi[k] = atomicAdd(&hist[b], 1);
      myb[k] = b;
      mye[k] = make_uint2((unsigned)src, (unsigned)dst);
    }
  }
  __syncthreads();
  if(t < MAXBUCK) scanb[t] = hist[t];
  __syncthreads();
  for(int off = 1; off < MAXBUCK; off <<= 1){
    int v = (t < MAXBUCK && t >= off) ? scanb[t - off] : 0;
    __syncthreads();
    if(t < MAXBUCK) scanb[t] += v;
    __syncthreads();
  }
  if(t < MAXBUCK){
    int excl = scanb[t] - hist[t];
    int gb = (hist[t] > 0) ? atomicAdd(&bcur[t], hist[t]) : 0;
    delta[t] = t * ECAP + gb - excl;            // fixed slab base + claimed offset
    scanb[t] = excl;
  }
  __syncthreads();
  #pragma unroll
  for(int k = 0; k < 16; k++){
    if(myb[k] >= 0) buf[scanb[myb[k]] + myi[k]] = mye[k];
  }
  __syncthreads();
  int total = min(4096, Etot - base);
  for(int i = t; i < total; i += 256){
    uint2 ed = buf[i];
    int b = (int)(ed.y >> BSHIFT);
    staged[i + delta[b]] = ed;                  // contiguous runs per bucket slab
  }
}

// ---------------- fused: gemm layer-1 (blocks < gbl) || binA (blocks >= gbl) ------------------
__global__ __launch_bounds__(256) void k_gemm1_binA(const void* __restrict__ Av,
    const unsigned short* __restrict__ W, const float* __restrict__ a_src,
    const float* __restrict__ a_dst, const float* __restrict__ bias,
    unsigned int* __restrict__ hb, float* __restrict__ alpha_s, float* __restrict__ alpha_d,
    int nrows, const int* __restrict__ ei, int* __restrict__ bcur,
    uint2* __restrict__ staged, int E, int Etot, int gbl){
  extern __shared__ uint4 smem_dyn[];
  if((int)blockIdx.x < gbl)
    gemm_body<false>(smem_dyn, Av, W, a_src, a_dst, bias, hb, alpha_s, alpha_d, nrows,
                     (int)blockIdx.x);
  else
    binA_body(smem_dyn, ei, bcur, staged, E, Etot, (int)blockIdx.x - gbl);
}

// ---------------- layer-2 GEMM (standalone) ----------------
__global__ __launch_bounds__(256) void k_gemm2(const void* __restrict__ Av,
    const unsigned short* __restrict__ W, const float* __restrict__ a_src,
    const float* __restrict__ a_dst, unsigned int* __restrict__ hb,
    float* __restrict__ alpha_s, float* __restrict__ alpha_d, int nrows){
  __shared__ uint4 smem_s[SMEM_BYTES / 16];
  gemm_body<true>(smem_s, Av, W, a_src, a_dst, nullptr, hb, alpha_s, alpha_d, nrows,
                  (int)blockIdx.x);
}

// per bucket (512 thr): scan bucket counts (global offset), degree-count 256 nodes, scan,
// write rowptr, place edges into the dense esrc window. Count/place passes stride 512.
__global__ __launch_bounds__(512) void k_binB(const uint2* __restrict__ staged,
    const int* __restrict__ bcur, int* __restrict__ rowptr, int* __restrict__ esrc, int n){
  __shared__ int sc[MAXBUCK];
  __shared__ int dcnt[1 << BSHIFT];
  __shared__ int doff[1 << BSHIFT];
  const int b = blockIdx.x;
  const int n0 = b << BSHIFT;
  const int t = threadIdx.x;
  // 256-wide scan of final bucket counts -> global CSR offset of this bucket
  if(t < MAXBUCK) sc[t] = bcur[t];
  __syncthreads();
  for(int off = 1; off < MAXBUCK; off <<= 1){
    int x = (t < MAXBUCK && t >= off) ? sc[t - off] : 0;
    __syncthreads();
    if(t < MAXBUCK) sc[t] += x;
    __syncthreads();
  }
  const int cnt = bcur[b];
  const int lo = sc[b] - cnt;
  if(t == 0 && b == (int)gridDim.x - 1) rowptr[n] = sc[MAXBUCK - 1];
  const uint2* run = staged + (size_t)b * ECAP;
  if(t < (1 << BSHIFT)) dcnt[t] = 0;
  __syncthreads();
  for(int j = t; j < cnt; j += 512){
    uint2 ed = run[j];
    atomicAdd(&dcnt[(int)(ed.y) - n0], 1);
  }
  __syncthreads();
  int v = 0;
  if(t < (1 << BSHIFT)){ v = dcnt[t]; doff[t] = v; }
  __syncthreads();
  for(int off = 1; off < (1 << BSHIFT); off <<= 1){
    int x = (t < (1 << BSHIFT) && t >= off) ? doff[t - off] : 0;
    __syncthreads();
    if(t < (1 << BSHIFT)) doff[t] += x;
    __syncthreads();
  }
  if(t < (1 << BSHIFT)){
    int excl = doff[t] - v;
    int i = n0 + t;
    if(i < n) rowptr[i] = lo + excl;
    dcnt[t] = excl;               // reuse as placement cursor
  }
  __syncthreads();
  for(int j = t; j < cnt; j += 512){
    uint2 ed = run[j];
    int pos = atomicAdd(&dcnt[(int)(ed.y) - n0], 1);
    esrc[lo + pos] = (int)ed.x;
  }
}

// ---------------- full-wave GAT for one node (v2-proven path; used as rare fallback) ----------
static __device__ __forceinline__ void gat_fullwave(const unsigned int* __restrict__ hb,
    const int* __restrict__ esrc, const float* __restrict__ a_s,
    const float* __restrict__ a_d, const float* __restrict__ bias,
    unsigned int* __restrict__ hb_out, uint2* pairs_w,
    int w, int s0, int s1, int lane, int n){
  const int deg = s1 - s0;
  const float adv = a_d[w];
  float2 acc0 = make_float2(0.f, 0.f), acc1 = make_float2(0.f, 0.f);
  float2 acc2 = make_float2(0.f, 0.f), acc3 = make_float2(0.f, 0.f);
  if(deg <= 64){
    int srcl = 0;
    if(lane < deg){
      srcl = esrc[s0 + lane];
      srcl = ((unsigned)srcl < (unsigned)n) ? srcl : 0;
    }
    int i0 = __shfl(srcl, 0), i1 = __shfl(srcl, 1);
    int i2 = __shfl(srcl, 2), i3 = __shfl(srcl, 3);
    int i4 = __shfl(srcl, 4), i5 = __shfl(srcl, 5);
    int i6 = __shfl(srcl, 6), i7 = __shfl(srcl, 7);
    unsigned int u0 = hb[(((unsigned)i0) << 6) + lane];
    unsigned int u1 = hb[(((unsigned)i1) << 6) + lane];
    unsigned int u2 = hb[(((unsigned)i2) << 6) + lane];
    unsigned int u3 = hb[(((unsigned)i3) << 6) + lane];
    unsigned int u4 = hb[(((unsigned)i4) << 6) + lane];
    unsigned int u5 = hb[(((unsigned)i5) << 6) + lane];
    unsigned int u6 = hb[(((unsigned)i6) << 6) + lane];
    unsigned int u7 = hb[(((unsigned)i7) << 6) + lane];
    float e = -1e30f;
    if(lane < deg){
      float v = a_s[srcl] + adv;
      e = v > 0.f ? v : NEG_SLOPE * v;
    }
    float m = e;
    #pragma unroll
    for(int o = 32; o; o >>= 1) m = fmaxf(m, __shfl_xor(m, o));
    float wgt = (lane < deg) ? __expf(e - m) : 0.f;
    float den = wgt;
    #pragma unroll
    for(int o = 32; o; o >>= 1) den += __shfl_xor(den, o);
    float winv = (den > 0.f) ? wgt / den : 0.f;
    pairs_w[lane] = make_uint2((unsigned)srcl, __float_as_uint(winv));
    float w0 = __shfl(winv, 0), w1 = __shfl(winv, 1);
    float w2 = __shfl(winv, 2), w3 = __shfl(winv, 3);
    float w4 = __shfl(winv, 4), w5 = __shfl(winv, 5);
    float w6 = __shfl(winv, 6), w7 = __shfl(winv, 7);
    acc0.x += w0 * b2f((unsigned short)(u0 & 0xffffu)); acc0.y += w0 * b2f((unsigned short)(u0 >> 16));
    acc1.x += w1 * b2f((unsigned short)(u1 & 0xffffu)); acc1.y += w1 * b2f((unsigned short)(u1 >> 16));
    acc2.x += w2 * b2f((unsigned short)(u2 & 0xffffu)); acc2.y += w2 * b2f((unsigned short)(u2 >> 16));
    acc3.x += w3 * b2f((unsigned short)(u3 & 0xffffu)); acc3.y += w3 * b2f((unsigned short)(u3 >> 16));
    acc0.x += w4 * b2f((unsigned short)(u4 & 0xffffu)); acc0.y += w4 * b2f((unsigned short)(u4 >> 16));
    acc1.x += w5 * b2f((unsigned short)(u5 & 0xffffu)); acc1.y += w5 * b2f((unsigned short)(u5 >> 16));
    acc2.x += w6 * b2f((unsigned short)(u6 & 0xffffu)); acc2.y += w6 * b2f((unsigned short)(u6 >> 16));
    acc3.x += w7 * b2f((unsigned short)(u7 & 0xffffu)); acc3.y += w7 * b2f((unsigned short)(u7 >> 16));
    int jj = 8;
    for(; jj + 8 <= deg; jj += 8){
      uint2 p0 = pairs_w[jj + 0], p1 = pairs_w[jj + 1];
      uint2 p2 = pairs_w[jj + 2], p3 = pairs_w[jj + 3];
      uint2 p4 = pairs_w[jj + 4], p5 = pairs_w[jj + 5];
      uint2 p6 = pairs_w[jj + 6], p7 = pairs_w[jj + 7];
      unsigned int v0 = hb[(p0.x << 6) + lane];
      unsigned int v1 = hb[(p1.x << 6) + lane];
      unsigned int v2 = hb[(p2.x << 6) + lane];
      unsigned int v3 = hb[(p3.x << 6) + lane];
      unsigned int v4 = hb[(p4.x << 6) + lane];
      unsigned int v5 = hb[(p5.x << 6) + lane];
      unsigned int v6 = hb[(p6.x << 6) + lane];
      unsigned int v7 = hb[(p7.x << 6) + lane];
      float q0 = __uint_as_float(p0.y), q1 = __uint_as_float(p1.y);
      float q2 = __uint_as_float(p2.y), q3 = __uint_as_float(p3.y);
      float q4 = __uint_as_float(p4.y), q5 = __uint_as_float(p5.y);
      float q6 = __uint_as_float(p6.y), q7 = __uint_as_float(p7.y);
      acc0.x += q0 * b2f((unsigned short)(v0 & 0xffffu)); acc0.y += q0 * b2f((unsigned short)(v0 >> 16));
      acc1.x += q1 * b2f((unsigned short)(v1 & 0xffffu)); acc1.y += q1 * b2f((unsigned short)(v1 >> 16));
      acc2.x += q2 * b2f((unsigned short)(v2 & 0xffffu)); acc2.y += q2 * b2f((unsigned short)(v2 >> 16));
      acc3.x += q3 * b2f((unsigned short)(v3 & 0xffffu)); acc3.y += q3 * b2f((unsigned short)(v3 >> 16));
      acc0.x += q4 * b2f((unsigned short)(v4 & 0xffffu)); acc0.y += q4 * b2f((unsigned short)(v4 >> 16));
      acc1.x += q5 * b2f((unsigned short)(v5 & 0xffffu)); acc1.y += q5 * b2f((unsigned short)(v5 >> 16));
      acc2.x += q6 * b2f((unsigned short)(v6 & 0xffffu)); acc2.y += q6 * b2f((unsigned short)(v6 >> 16));
      acc3.x += q7 * b2f((unsigned short)(v7 & 0xffffu)); acc3.y += q7 * b2f((unsigned short)(v7 >> 16));
    }
    for(; jj < deg; jj++){
      uint2 p = pairs_w[jj];
      unsigned int v = hb[(p.x << 6) + lane];
      float q = __uint_as_float(p.y);
      acc0.x += q * b2f((unsigned short)(v & 0xffffu));
      acc0.y += q * b2f((unsigned short)(v >> 16));
    }
  } else {
    float m = -1e30f;
    for(int j = s0 + lane; j < s1; j += 64){
      int s = esrc[j]; s = ((unsigned)s < (unsigned)n) ? s : 0;
      float e = a_s[s] + adv;
      e = e > 0.f ? e : NEG_SLOPE * e;
      m = fmaxf(m, e);
    }
    #pragma unroll
    for(int o = 32; o; o >>= 1) m = fmaxf(m, __shfl_xor(m, o));
    float den = 0.f;
    for(int j = s0 + lane; j < s1; j += 64){
      int s = esrc[j]; s = ((unsigned)s < (unsigned)n) ? s : 0;
      float e = a_s[s] + adv;
      e = e > 0.f ? e : NEG_SLOPE * e;
      den += __expf(e - m);
    }
    #pragma unroll
    for(int o = 32; o; o >>= 1) den += __shfl_xor(den, o);
    float inv = (den > 0.f) ? 1.f / den : 0.f;
    for(int j = s0; j < s1; j++){
      int s = esrc[j]; s = ((unsigned)s < (unsigned)n) ? s : 0;
      float e = a_s[s] + adv;
      e = e > 0.f ? e : NEG_SLOPE * e;
      float wv = __expf(e - m) * inv;
      unsigned int u = hb[(((unsigned)s) << 6) + lane];
      acc0.x += wv * b2f((unsigned short)(u & 0xffffu));
      acc0.y += wv * b2f((unsigned short)(u >> 16));
    }
  }
  float2 bl = ((const float2*)bias)[lane];
  float ox = (acc0.x + acc1.x) + (acc2.x + acc3.x) + bl.x;
  float oy = (acc0.y + acc1.y) + (acc2.y + acc3.y) + bl.y;
  ox = 0.5f * (ox + fabsf(ox));   // NaN-transparent relu
  oy = 0.5f * (oy + fabsf(oy));
  hb_out[(size_t)w * 64 + lane] = pack_bf2(ox, oy);
}

// 8 features accumulate for one dual-row uint4 fragment
#define ACC8(U, WQ) do{ float _w = (WQ); \
  acc0.x += _w * b2f((unsigned short)((U).x & 0xffffu)); \
  acc0.y += _w * b2f((unsigned short)((U).x >> 16)); \
  acc0.z += _w * b2f((unsigned short)((U).y & 0xffffu)); \
  acc0.w += _w * b2f((unsigned short)((U).y >> 16)); \
  acc1.x += _w * b2f((unsigned short)((U).z & 0xffffu)); \
  acc1.y += _w * b2f((unsigned short)((U).z >> 16)); \
  acc1.z += _w * b2f((unsigned short)((U).w & 0xffffu)); \
  acc1.w += _w * b2f((unsigned short)((U).w >> 16)); }while(0)

// ---------------- GAT: 2 nodes/wave, 16-edge batches via dual-row uint4 loads (round-6 best) --
// Lanes 0-31 node A, 32-63 node B. Within a half: lanes 0-15 handle even edges, 16-31 odd
// (sub = hl>>4), each reading 16 B (8 features) of the row -> one load instr covers 2 edges.
// Batch A = edges 0..15 issued BEFORE softmax; batch B = edges 16..31 via LDS pairs (weights 0
// beyond deg; padding reads row 0 = cache-hot). Pair-split recombined with 8 shfl_xor(16).
// deg>32 in either half -> wave-uniform fallback to full-wave path (~1e-4 of nodes).
__global__ __launch_bounds__(256) void k_gat(const unsigned int* __restrict__ hb,
    const int* __restrict__ rowptr, const int* __restrict__ esrc,
    const float* __restrict__ a_s, const float* __restrict__ a_d,
    const float* __restrict__ bias, unsigned int* __restrict__ hb_out, int n, int Etot){
  __shared__ uint2 pairs[4][64];              // per-wave (srcl, winv) stash, 2 KB
  const int t = threadIdx.x;
  const int lane = t & 63;
  const int wvid = t >> 6;
  const int nA = blockIdx.x * 8 + wvid * 2;   // 8 nodes per block (2 per wave)
  if(nA >= n) return;
  const int nB = nA + 1;
  int r0 = rowptr[nA];
  int r1 = rowptr[nA + 1];
  int r2 = (nB < n) ? rowptr[nB + 1] : r1;
  r0 = max(0, min(r0, Etot));
  r1 = max(r0, min(r1, Etot));
  r2 = max(r1, min(r2, Etot));
  const int degA = r1 - r0, degB = r2 - r1;

  if(degA <= 32 && degB <= 32){
    const int half = lane >> 5;               // 0: node A, 1: node B
    const int hl = lane & 31;
    const int sub = hl >> 4;                  // 0: even edge of pair, 1: odd edge
    const int fl = hl & 15;                   // 16B feature chunk (features 8fl..8fl+7)
    const int w = nA + half;
    const int s0 = half ? r1 : r0;
    const int deg = half ? degB : degA;
    const float adv = (w < n) ? a_d[w] : 0.f;
    const uint4* __restrict__ hb4 = (const uint4*)hb;   // row = 16 uint4
    float4 acc0 = make_float4(0.f, 0.f, 0.f, 0.f);
    float4 acc1 = make_float4(0.f, 0.f, 0.f, 0.f);

    int srcl = 0;
    if(hl < deg){
      srcl = esrc[s0 + hl];
      srcl = ((unsigned)srcl < (unsigned)n) ? srcl : 0;
    }
    const int hb0 = lane & 32;
    // batch A: edges 0..15 via 8 dual-row loads, issued before softmax
    int e0 = __shfl(srcl, hb0 + 0  + sub);
    int e1 = __shfl(srcl, hb0 + 2  + sub);
    int e2 = __shfl(srcl, hb0 + 4  + sub);
    int e3 = __shfl(srcl, hb0 + 6  + sub);
    int e4 = __shfl(srcl, hb0 + 8  + sub);
    int e5 = __shfl(srcl, hb0 + 10 + sub);
    int e6 = __shfl(srcl, hb0 + 12 + sub);
    int e7 = __shfl(srcl, hb0 + 14 + sub);
    uint4 u0 = hb4[(((unsigned)e0) << 4) + fl];
    uint4 u1 = hb4[(((unsigned)e1) << 4) + fl];
    uint4 u2 = hb4[(((unsigned)e2) << 4) + fl];
    uint4 u3 = hb4[(((unsigned)e3) << 4) + fl];
    uint4 u4 = hb4[(((unsigned)e4) << 4) + fl];
    uint4 u5 = hb4[(((unsigned)e5) << 4) + fl];
    uint4 u6 = hb4[(((unsigned)e6) << 4) + fl];
    uint4 u7 = hb4[(((unsigned)e7) << 4) + fl];
    // softmax (hidden under load latency); reductions stay within the 32-lane half
    float e = -1e30f;
    if(hl < deg){
      float v = a_s[srcl] + adv;
      e = v > 0.f ? v : NEG_SLOPE * v;
    }
    float m = e;
    #pragma unroll
    for(int o = 16; o; o >>= 1) m = fmaxf(m, __shfl_xor(m, o));
    float wgt = (hl < deg) ? __expf(e - m) : 0.f;
    float den = wgt;
    #pragma unroll
    for(int o = 16; o; o >>= 1) den += __shfl_xor(den, o);
    float winv = (den > 0.f) ? wgt / den : 0.f;   // lanes >= deg -> 0
    pairs[wvid][lane] = make_uint2((unsigned)srcl, __float_as_uint(winv));
    // consume batch A
    float w0 = __shfl(winv, hb0 + 0  + sub);
    float w1 = __shfl(winv, hb0 + 2  + sub);
    float w2 = __shfl(winv, hb0 + 4  + sub);
    float w3 = __shfl(winv, hb0 + 6  + sub);
    float w4 = __shfl(winv, hb0 + 8  + sub);
    float w5 = __shfl(winv, hb0 + 10 + sub);
    float w6 = __shfl(winv, hb0 + 12 + sub);
    float w7 = __shfl(winv, hb0 + 14 + sub);
    ACC8(u0, w0); ACC8(u1, w1); ACC8(u2, w2); ACC8(u3, w3);
    ACC8(u4, w4); ACC8(u5, w5); ACC8(u6, w6); ACC8(u7, w7);
    // batch B: edges 16..31 (half-divergent branch; masked lanes issue nothing)
    if(deg > 16){
      uint2 p0 = pairs[wvid][hb0 + 16 + sub];
      uint2 p1 = pairs[wvid][hb0 + 18 + sub];
      uint2 p2 = pairs[wvid][hb0 + 20 + sub];
      uint2 p3 = pairs[wvid][hb0 + 22 + sub];
      uint2 p4 = pairs[wvid][hb0 + 24 + sub];
      uint2 p5 = pairs[wvid][hb0 + 26 + sub];
      uint2 p6 = pairs[wvid][hb0 + 28 + sub];
      uint2 p7 = pairs[wvid][hb0 + 30 + sub];
      uint4 v0 = hb4[(p0.x << 4) + fl];
      uint4 v1 = hb4[(p1.x << 4) + fl];
      uint4 v2 = hb4[(p2.x << 4) + fl];
      uint4 v3 = hb4[(p3.x << 4) + fl];
      uint4 v4 = hb4[(p4.x << 4) + fl];
      uint4 v5 = hb4[(p5.x << 4) + fl];
      uint4 v6 = hb4[(p6.x << 4) + fl];
      uint4 v7 = hb4[(p7.x << 4) + fl];
      ACC8(v0, __uint_as_float(p0.y)); ACC8(v1, __uint_as_float(p1.y));
      ACC8(v2, __uint_as_float(p2.y)); ACC8(v3, __uint_as_float(p3.y));
      ACC8(v4, __uint_as_float(p4.y)); ACC8(v5, __uint_as_float(p5.y));
      ACC8(v6, __uint_as_float(p6.y)); ACC8(v7, __uint_as_float(p7.y));
    }
    // recombine even/odd edge sub-accumulators
    acc0.x += __shfl_xor(acc0.x, 16); acc0.y += __shfl_xor(acc0.y, 16);
    acc0.z += __shfl_xor(acc0.z, 16); acc0.w += __shfl_xor(acc0.w, 16);
    acc1.x += __shfl_xor(acc1.x, 16); acc1.y += __shfl_xor(acc1.y, 16);
    acc1.z += __shfl_xor(acc1.z, 16); acc1.w += __shfl_xor(acc1.w, 16);
    if(w < n && sub == 0){
      float4 b0 = ((const float4*)bias)[2 * fl];
      float4 b1 = ((const float4*)bias)[2 * fl + 1];
      float f0 = acc0.x + b0.x, f1 = acc0.y + b0.y;
      float f2 = acc0.z + b0.z, f3 = acc0.w + b0.w;
      float f4 = acc1.x + b1.x, f5 = acc1.y + b1.y;
      float f6 = acc1.z + b1.z, f7 = acc1.w + b1.w;
      f0 = 0.5f * (f0 + fabsf(f0)); f1 = 0.5f * (f1 + fabsf(f1));   // NaN-transparent relu
      f2 = 0.5f * (f2 + fabsf(f2)); f3 = 0.5f * (f3 + fabsf(f3));
      f4 = 0.5f * (f4 + fabsf(f4)); f5 = 0.5f * (f5 + fabsf(f5));
      f6 = 0.5f * (f6 + fabsf(f6)); f7 = 0.5f * (f7 + fabsf(f7));
      ((uint4*)hb_out)[((size_t)w << 4) + fl] =
        make_uint4(pack_bf2(f0, f1), pack_bf2(f2, f3), pack_bf2(f4, f5), pack_bf2(f6, f7));
    }
  } else {
    // rare: some half has deg > 32 -> full-wave per node
    gat_fullwave(hb, esrc, a_s, a_d, bias, hb_out, &pairs[wvid][0], nA, r0, r1, lane, n);
    if(nB < n)
      gat_fullwave(hb, esrc, a_s, a_d, bias, hb_out, &pairs[wvid][0], nB, r1, r2, lane, n);
  }
}

// ---------------- mean-pool (bf16 h) + fused head ----------------
__global__ __launch_bounds__(512) void k_poolout(const unsigned int* __restrict__ h2,
    const int* __restrict__ gs, const int* __restrict__ ge,
    const float* __restrict__ out_w, const float* __restrict__ out_b,
    float* __restrict__ out, int n){
  const int g = blockIdx.x;
  const int t = threadIdx.x;
  const int f2 = t & 63;          // packed-uint column (features 2*f2, 2*f2+1)
  const int rr = t >> 6;          // row phase 0..7
  int s = gs[g], e = ge[g];
  s = max(0, min(s, n)); e = max(s, min(e, n));
  float sx = 0.f, sy = 0.f;
  for(int i = s + rr; i < e; i += 8){
    unsigned int u = h2[(size_t)i * 64 + f2];
    sx += b2f((unsigned short)(u & 0xffffu));
    sy += b2f((unsigned short)(u >> 16));
  }
  __shared__ float part[8 * 128];
  part[rr * 128 + 2 * f2]     = sx;
  part[rr * 128 + 2 * f2 + 1] = sy;
  __syncthreads();
  __shared__ float red[2];
  if(t < 128){
    float tot = 0.f;
    #pragma unroll
    for(int r = 0; r < 8; r++) tot += part[r * 128 + t];
    int c = e - s;
    float invc = (c > 0) ? 1.f / (float)c : 0.f;
    float v = tot * invc * out_w[t];
    #pragma unroll
    for(int o = 32; o; o >>= 1) v += __shfl_xor(v, o);
    if((t & 63) == 0) red[t >> 6] = v;
  }
  __syncthreads();
  if(t == 0) out[g] = red[0] + red[1] + out_b[0];
}

extern "C" void kernel_launch(void* const* d_in, const int* in_sizes, int n_in,
                              void* d_out, int out_size, void* d_ws, size_t ws_size,
                              hipStream_t stream){
  const float* x     = (const float*)d_in[0];
  const int*   ei    = (const int*)d_in[1];
  const int*   batch = (const int*)d_in[2];
  const float* lin_w = (const float*)d_in[3];
  const float* lin_b = (const float*)d_in[4];
  const float* w1    = (const float*)d_in[5];
  const float* as1   = (const float*)d_in[6];
  const float* ad1   = (const float*)d_in[7];
  const float* b1    = (const float*)d_in[8];
  const float* w2    = (const float*)d_in[9];
  const float* as2   = (const float*)d_in[10];
  const float* ad2   = (const float*)d_in[11];
  const float* b2    = (const float*)d_in[12];
  const float* ow    = (const float*)d_in[13];
  const float* ob    = (const float*)d_in[14];
  float* out = (float*)d_out;

  const int N = in_sizes[0] / 128;
  const int E = in_sizes[1] / 2;
  const int Etot = E + N;
  const int G = out_size;
  const int nbuck = (N + (1 << BSHIFT) - 1) >> BSHIFT;

  auto a16 = [](size_t v){ return (v + 15) & ~(size_t)15; };
  char* p = (char*)d_ws;
  int*   rowptr  = (int*)p;   p += a16((size_t)(N + 1) * 4);
  int*   bcur    = (int*)p;   p += a16((size_t)MAXBUCK * 4);
  int*   gs      = (int*)p;   p += a16((size_t)G * 4);
  int*   ge      = (int*)p;   p += a16((size_t)G * 4);
  float* alpha_s = (float*)p; p += a16((size_t)N * 4);
  float* alpha_d = (float*)p; p += a16((size_t)N * 4);
  unsigned short* Wtc = (unsigned short*)p; p += (size_t)128 * 128 * 2;  // bf16-T(Win@W1)
  float* bc      = (float*)p; p += (size_t)128 * 4;                      // b_in@W1
  unsigned short* Wt2 = (unsigned short*)p; p += (size_t)128 * 128 * 2;  // bf16-T(w2)
  int*   esrc    = (int*)p;   p += a16((size_t)Etot * 4);
  uint2* staged  = (uint2*)p; p += (size_t)MAXBUCK * ECAP * 8;           // fixed slabs
  unsigned int* hb  = (unsigned int*)p; p += (size_t)N * 64 * 4;  // projection, bf16-packed
  unsigned int* hb2 = (unsigned int*)p; p += (size_t)N * 64 * 4;  // h1 / h2, bf16-packed

  const int cbl = (Etot + 4095) / 4096;
  const int gbl = (N + 63) / 64;
  const int wbl = (N + 7) / 8;

  k_setup<<<6 + (N + 255) / 256, 256, 0, stream>>>(lin_w, lin_b, w1, w2, Wtc, bc, Wt2,
                                                   batch, bcur, gs, ge, N);
  // gemm layer-1 and binA are independent (both depend only on setup) -> one overlapped launch
  k_gemm1_binA<<<gbl + cbl, 256, SMEM_BYTES, stream>>>(x, Wtc, as1, ad1, bc, hb,
                                                       alpha_s, alpha_d, N,
                                                       ei, bcur, staged, E, Etot, gbl);
  k_binB<<<nbuck, 512, 0, stream>>>(staged, bcur, rowptr, esrc, N);
  k_gat<<<wbl, 256, 0, stream>>>(hb, rowptr, esrc, alpha_s, alpha_d, b1, hb2, N, Etot);
  k_gemm2<<<gbl, 256, 0, stream>>>(hb2, Wt2, as2, ad2, hb, alpha_s, alpha_d, N);
  k_gat<<<wbl, 256, 0, stream>>>(hb, rowptr, esrc, alpha_s, alpha_d, b2, hb2, N, Etot);
  k_poolout<<<G, 512, 0, stream>>>(hb2, gs, ge, ow, ob, out, N);
}